// Round 6
// baseline (263.970 us; speedup 1.0000x reference)
//
#include <hip/hip_runtime.h>
#include <math.h>

#define NN 100000
#define NE 1600000
#define DD 128          // D_IN == D_OUT
#define NBINS 3125      // 32-node bins: 100000/32 exactly
#define CAP 640         // per-bin capacity; Poisson(512) max over 3125 bins ~615 (5.7 sigma)
#define PB 196          // partition blocks (8192 edges each, 1024 threads)
#define CB 196          // conv blocks (grid-stride)

// ---------------------------------------------------------------------------
// d_ws layout (int32 units), ~33.7 MB used:
//   Hh      [NN*DD fp16]    @ WS_HH   (25.6 MB)
//   cursor  [NBINS]         @ WS_CUR  (zeroed via hipMemsetAsync)
//   entries [NBINS*CAP]     @ WS_ENT  (8.0 MB; packed (src&31)<<17 | dst)
//   Ah      [NN*DD fp16]    @ WS_AH   (25.6 MB)
//   Wh      [128*256 fp16]  @ WS_WH   (64 KB; W pre-converted in prep)
// ---------------------------------------------------------------------------
#define WS_HH  0
#define WS_CUR 6400000
#define WS_ENT (WS_CUR + NBINS)
#define WS_AH  (WS_ENT + NBINS * CAP)
#define WS_WH  (WS_AH + NN * (DD / 2))

typedef __attribute__((ext_vector_type(8))) _Float16 h8_t;
typedef __attribute__((ext_vector_type(4))) _Float16 h4_t;
typedef __attribute__((ext_vector_type(2))) _Float16 h2_t;
typedef __attribute__((ext_vector_type(4))) float f4_t;

// packed fp32x2 -> fp16x2 (RNE via v_cvt)
__device__ __forceinline__ unsigned pk2h(float x, float y) {
    h2_t h;
    h.x = (_Float16)x;
    h.y = (_Float16)y;
    return *(unsigned*)&h;
}

__device__ __forceinline__ h4_t h4max(h4_t a, h4_t b) {
    return __builtin_elementwise_max(a, b);   // 2x v_pk_max_f16
}

// ---------------------------------------------------------------------------
// Fused prep: blocks [0,PB) partition edges into per-bin regions; blocks
// [PB,PB+CB) convert H fp32 -> fp16 (grid-stride); block PB+CB converts
// W fp32 -> fp16 (64 KB, one block).
// ---------------------------------------------------------------------------
__global__ __launch_bounds__(1024) void prep_kernel(const float* __restrict__ H,
                                                    const int* __restrict__ src,
                                                    const int* __restrict__ dst,
                                                    int* __restrict__ cursor,
                                                    unsigned* __restrict__ entries,
                                                    uint4* __restrict__ Hh4,
                                                    const float* __restrict__ W,
                                                    unsigned* __restrict__ Wh) {
    __shared__ int cnt[NBINS];    // 12.5 KB
    __shared__ int gcur[NBINS];   // 12.5 KB
    const int t = threadIdx.x;
    const int b = blockIdx.x;
    if (b < PB) {
        for (int i = t; i < NBINS; i += 1024) cnt[i] = 0;
        __syncthreads();
        const int base = b * 8192;
        int sv[8];
#pragma unroll
        for (int k = 0; k < 8; ++k) {
            int e = base + k * 1024 + t;
            sv[k] = (e < NE) ? src[e] : -1;
            if (sv[k] >= 0) atomicAdd(&cnt[sv[k] >> 5], 1);
        }
        __syncthreads();
        for (int i = t; i < NBINS; i += 1024) {
            int c = cnt[i];
            gcur[i] = c ? i * CAP + atomicAdd(&cursor[i], c) : 0;
        }
        __syncthreads();
#pragma unroll
        for (int k = 0; k < 8; ++k) {
            int e = base + k * 1024 + t;
            if (sv[k] >= 0) {
                int s = sv[k];
                int pos = atomicAdd(&gcur[s >> 5], 1);
                entries[pos] = ((unsigned)(s & 31) << 17) | (unsigned)dst[e];
            }
        }
    } else if (b < PB + CB) {
        const int nb = b - PB;
        const int n8 = NN * DD / 8;   // 1.6M tasks of 8 elems
        for (int i = nb * 1024 + t; i < n8; i += CB * 1024) {
            const float4* s = (const float4*)H + (size_t)i * 2;
            float4 a = s[0], c4 = s[1];
            uint4 o;
            o.x = pk2h(a.x, a.y);
            o.y = pk2h(a.z, a.w);
            o.z = pk2h(c4.x, c4.y);
            o.w = pk2h(c4.z, c4.w);
            Hh4[i] = o;
        }
    } else {
        // W fp32 [128][256] -> fp16, 16384 uint outputs over 1024 threads
        for (int i = t; i < 128 * 256 / 2; i += 1024)
            Wh[i] = pk2h(W[2 * i], W[2 * i + 1]);
    }
}

// ---------------------------------------------------------------------------
// Atomic-free per-bin segment-max, 32-node bins. Grid 3125 -> 12.2 blocks/CU
// oversubscribed, waves-cap 8 blocks/CU => ~100% occupancy (vs 53% at 64-node
// bins where grid 1563 = 6.1/CU was the limit; R5 proved gather rate scales
// with resident waves). Counting-sort by local node, then each wave processes
// 8 whole nodes: h4 loads per 32-lane half, 4 rows in flight/half, halves
// combined via shfl_xor(32). LDS 5.6 KB, VGPR ~20.
// ---------------------------------------------------------------------------
__global__ __launch_bounds__(256) void agg_kernel(const _Float16* __restrict__ Hh,
                                                  const int* __restrict__ cursor,
                                                  const unsigned* __restrict__ entries,
                                                  unsigned* __restrict__ Ah) {
    __shared__ unsigned raw[CAP];
    __shared__ unsigned sorted[CAP];
    __shared__ int cnt[32], base_s[32], cur[32];
    const int t = threadIdx.x;
    const int b = blockIdx.x;
    const int n = cursor[b];

    if (t < 32) cnt[t] = 0;
    __syncthreads();
    for (int i = t; i < n; i += 256) {
        unsigned e = entries[b * CAP + i];
        raw[i] = e;
        atomicAdd(&cnt[e >> 17], 1);
    }
    __syncthreads();
    if (t < 32) {   // lanes 0..31 of wave 0: width-32 inclusive scan
        int v = cnt[t];
        int incl = v;
#pragma unroll
        for (int o = 1; o < 32; o <<= 1) {
            int y = __shfl_up(incl, o, 32);
            if (t >= o) incl += y;
        }
        base_s[t] = incl - v;
        cur[t] = incl - v;
    }
    __syncthreads();
    for (int i = t; i < n; i += 256) {
        unsigned e = raw[i];
        int pos = atomicAdd(&cur[e >> 17], 1);
        sorted[pos] = e & 0x1FFFFu;
    }
    __syncthreads();

    const int lane = t & 63;
    const int w = t >> 6;
    const int half = lane >> 5;        // 0/1: even/odd neighbor indices
    const int l32 = lane & 31;
    const _Float16* __restrict__ colbase = Hh + l32 * 4;   // 8B per lane
#pragma unroll
    for (int q = 0; q < 8; ++q) {
        int ln = w * 8 + q;
        int s0 = base_s[ln];
        int e0 = s0 + cnt[ln];
        unsigned long long mu = 0xFC00FC00FC00FC00ull;   // 4x -inf fp16
        h4_t m = *(h4_t*)&mu;
        int j = s0 + half;
        for (; j + 6 < e0; j += 8) {                     // 4 rows in flight/half
            int d0 = sorted[j], d1 = sorted[j + 2];
            int d2 = sorted[j + 4], d3 = sorted[j + 6];
            h4_t v0 = *(const h4_t*)(colbase + (size_t)d0 * DD);
            h4_t v1 = *(const h4_t*)(colbase + (size_t)d1 * DD);
            h4_t v2 = *(const h4_t*)(colbase + (size_t)d2 * DD);
            h4_t v3 = *(const h4_t*)(colbase + (size_t)d3 * DD);
            m = h4max(m, h4max(h4max(v0, v1), h4max(v2, v3)));
        }
        for (; j < e0; j += 2) {
            h4_t v0 = *(const h4_t*)(colbase + (size_t)sorted[j] * DD);
            m = h4max(m, v0);
        }
        // combine halves: each lane gets partner lane^32's partial max
        uint2 mv = *(uint2*)&m;
        uint2 ov;
        ov.x = (unsigned)__shfl_xor((int)mv.x, 32, 64);
        ov.y = (unsigned)__shfl_xor((int)mv.y, 32, 64);
        h4_t om = *(h4_t*)&ov;
        m = h4max(m, om);
        int node = b * 32 + ln;
        if (half == 0 && node < NN) {
            uint2 outv = make_uint2(0u, 0u);
            if (s0 < e0) outv = *(uint2*)&m;
            *(uint2*)(Ah + (size_t)node * 64 + l32 * 2) = outv;
        }
    }
}

// ---------------------------------------------------------------------------
// fp16 MFMA matmul v3: LDS-free, barrier-free. 64 rows x 128 outs per block
// (grid 1563), 4 waves, wave w owns C rows w*16..+15. A-fragments loaded
// directly from Hh/Ah (block-exclusive rows, each 16B read exactly once; a
// wave's load = 16 rows x 64B chunks). B-fragments directly from Wh (64 KB,
// L2-hot broadcast). Frag layouts (m89/m91): A[m=lane&15][k=quad*8+j],
// B[k=quad*8+j][n=lane&15], C/D row=quad*4+reg, col=lane&15.
// ---------------------------------------------------------------------------
__global__ __launch_bounds__(256) void mfma_matmul_kernel(
        const unsigned short* __restrict__ Hh,   // [NN][128] fp16
        const unsigned short* __restrict__ Ah,   // [NN][128] fp16
        const unsigned short* __restrict__ Wh,   // [128][256] fp16
        const float* __restrict__ bias,          // [128]
        float* __restrict__ out) {               // [NN][128] fp32
    const int t = threadIdx.x;
    const int lane = t & 63;
    const int w = t >> 6;
    const int quad = lane >> 4;
    const int l16 = lane & 15;
    const int arow = blockIdx.x * 64 + w * 16 + l16;
    const bool aok = arow < NN;

    f4_t acc[8] = {};
#pragma unroll
    for (int c = 0; c < 4; ++c) {
        const unsigned short* xb = (c < 2) ? Hh : Ah;
        const int koff = (c & 1) * 64;
#pragma unroll
        for (int kk = 0; kk < 64; kk += 32) {
            uint4 av = make_uint4(0, 0, 0, 0);
            if (aok)
                av = *(const uint4*)(xb + (size_t)arow * DD + koff + kk + quad * 8);
            h8_t a = *(h8_t*)&av;
#pragma unroll
            for (int ot = 0; ot < 8; ++ot) {
                h8_t bf = *(const h8_t*)(Wh + (size_t)(ot * 16 + l16) * 256
                                         + c * 64 + kk + quad * 8);
                acc[ot] = __builtin_amdgcn_mfma_f32_16x16x32_f16(a, bf, acc[ot], 0, 0, 0);
            }
        }
    }

#pragma unroll
    for (int ot = 0; ot < 8; ++ot) {
        float bv = bias[ot * 16 + l16];
#pragma unroll
        for (int reg = 0; reg < 4; ++reg) {
            int row = blockIdx.x * 64 + w * 16 + quad * 4 + reg;
            if (row < NN)
                out[(size_t)row * DD + ot * 16 + l16] = acc[ot][reg] + bv;
        }
    }
}

extern "C" void kernel_launch(void* const* d_in, const int* in_sizes, int n_in,
                              void* d_out, int out_size, void* d_ws, size_t ws_size,
                              hipStream_t stream) {
    const float* H   = (const float*)d_in[0];
    const int*   src = (const int*)d_in[1];
    const int*   dst = (const int*)d_in[2];
    const float* W   = (const float*)d_in[3];
    const float* b   = (const float*)d_in[4];
    float* out = (float*)d_out;

    int* ws = (int*)d_ws;
    unsigned short* Hh      = (unsigned short*)(ws + WS_HH);
    int*            cursor  = ws + WS_CUR;
    unsigned*       entries = (unsigned*)(ws + WS_ENT);
    unsigned*       Ah      = (unsigned*)(ws + WS_AH);
    unsigned*       Wh      = (unsigned*)(ws + WS_WH);

    hipMemsetAsync(cursor, 0, NBINS * sizeof(int), stream);
    prep_kernel<<<PB + CB + 1, 1024, 0, stream>>>(H, src, dst, cursor, entries,
                                                  (uint4*)Hh, W, Wh);
    agg_kernel<<<NBINS, 256, 0, stream>>>((const _Float16*)Hh, cursor, entries, Ah);
    mfma_matmul_kernel<<<(NN + 63) / 64, 256, 0, stream>>>(
        Hh, (const unsigned short*)Ah, (const unsigned short*)Wh, b, out);
}

// Round 7
// 236.027 us; speedup vs baseline: 1.1184x; 1.1184x over previous
//
#include <hip/hip_runtime.h>
#include <math.h>

#define NN 100000
#define NE 1600000
#define DD 128          // D_IN == D_OUT
#define NB 1563         // 64-node bins: ceil(100000/64)
#define CAP 1280        // per-bin entry capacity; Poisson(1024) max over 1563 bins ~1147
#define PB 196          // partition blocks (8192 edges each, 1024 threads)
#define CB 196          // conv blocks (grid-stride)

// ---------------------------------------------------------------------------
// d_ws layout (int32 units), ~33.7 MB used:
//   Hh      [NN*DD fp16]    @ WS_HH   (25.6 MB)
//   cursor  [NB]            @ WS_CUR  (zeroed via hipMemsetAsync)
//   entries [NB*CAP]        @ WS_ENT  (8.0 MB; packed (src&63)<<17 | dst)
//   Wh      [128*256 fp16]  @ WS_WH   (64 KB; W pre-converted in prep)
// ---------------------------------------------------------------------------
#define WS_HH  0
#define WS_CUR 6400000
#define WS_ENT (WS_CUR + NB)
#define WS_WH  (WS_ENT + NB * CAP)

typedef __attribute__((ext_vector_type(8))) _Float16 h8_t;
typedef __attribute__((ext_vector_type(4))) _Float16 h4_t;
typedef __attribute__((ext_vector_type(2))) _Float16 h2_t;
typedef __attribute__((ext_vector_type(4))) float f4_t;

// packed fp32x2 -> fp16x2 (RNE via v_cvt)
__device__ __forceinline__ unsigned pk2h(float x, float y) {
    h2_t h;
    h.x = (_Float16)x;
    h.y = (_Float16)y;
    return *(unsigned*)&h;
}

__device__ __forceinline__ h4_t h4max(h4_t a, h4_t b) {
    return __builtin_elementwise_max(a, b);   // 2x v_pk_max_f16
}

// ---------------------------------------------------------------------------
// Fused prep (R3-proven geometry): blocks [0,PB) partition edges into per-bin
// regions; blocks [PB,PB+CB) convert H fp32 -> fp16; block PB+CB converts W.
// ---------------------------------------------------------------------------
__global__ __launch_bounds__(1024) void prep_kernel(const float* __restrict__ H,
                                                    const int* __restrict__ src,
                                                    const int* __restrict__ dst,
                                                    int* __restrict__ cursor,
                                                    unsigned* __restrict__ entries,
                                                    uint4* __restrict__ Hh4,
                                                    const float* __restrict__ W,
                                                    unsigned* __restrict__ Wh) {
    __shared__ int cnt[NB];    // 6.25 KB
    __shared__ int gcur[NB];   // 6.25 KB
    const int t = threadIdx.x;
    const int b = blockIdx.x;
    if (b < PB) {
        for (int i = t; i < NB; i += 1024) cnt[i] = 0;
        __syncthreads();
        const int base = b * 8192;
        int sv[8];
#pragma unroll
        for (int k = 0; k < 8; ++k) {
            int e = base + k * 1024 + t;
            sv[k] = (e < NE) ? src[e] : -1;
            if (sv[k] >= 0) atomicAdd(&cnt[sv[k] >> 6], 1);
        }
        __syncthreads();
        for (int i = t; i < NB; i += 1024) {
            int c = cnt[i];
            gcur[i] = c ? i * CAP + atomicAdd(&cursor[i], c) : 0;
        }
        __syncthreads();
#pragma unroll
        for (int k = 0; k < 8; ++k) {
            int e = base + k * 1024 + t;
            if (sv[k] >= 0) {
                int s = sv[k];
                int pos = atomicAdd(&gcur[s >> 6], 1);
                entries[pos] = ((unsigned)(s & 63) << 17) | (unsigned)dst[e];
            }
        }
    } else if (b < PB + CB) {
        const int nb = b - PB;
        const int n8 = NN * DD / 8;   // 1.6M tasks of 8 elems
        for (int i = nb * 1024 + t; i < n8; i += CB * 1024) {
            const float4* s = (const float4*)H + (size_t)i * 2;
            float4 a = s[0], c4 = s[1];
            uint4 o;
            o.x = pk2h(a.x, a.y);
            o.y = pk2h(a.z, a.w);
            o.z = pk2h(c4.x, c4.y);
            o.w = pk2h(c4.z, c4.w);
            Hh4[i] = o;
        }
    } else {
        // W fp32 [128][256] -> fp16, 16384 uint outputs over 1024 threads
        for (int i = t; i < 128 * 256 / 2; i += 1024)
            Wh[i] = pk2h(W[2 * i], W[2 * i + 1]);
    }
}

// ---------------------------------------------------------------------------
// Fused agg + matmul, occupancy-preserving (vs R5's 53KB failure):
//   - H-half A-fragments prefetched from global at kernel START (own rows,
//     16B/lane, 64B/row chunks) -> resolved long before phase 3, 16 VGPR.
//   - gather output X holds ONLY the aggregated half: [64][XA=136] fp16,
//     17.4 KB padded (row stride 272B -> 2-way bank alias on frag reads).
//   - Ws [128][72] (18.4 KB) unions with dead raw/sorted buffers.
//   LDS ~36.6 KB -> 4 blocks/CU = 16 waves (solo agg had ~17). Matmul MFMA
//   rides in co-resident blocks' gather-miss shadows. Kills the mfma
//   dispatch (+12us gap), the 51MB Ah round-trip, and mfma's Hh re-read.
// Frag layouts (m89/m91): A[m=lane&15][k=quad*8+j], B[k][n=lane&15],
// C/D row=quad*4+reg, col=lane&15.
// ---------------------------------------------------------------------------
#define XP 72     // Ws row pitch (fp16): 144B
#define XA 136    // X row pitch (fp16): 272B
__global__ __launch_bounds__(256) void aggmat_kernel(
        const unsigned short* __restrict__ Hh,   // [NN][128] fp16
        const int* __restrict__ cursor,
        const unsigned* __restrict__ entries,
        const unsigned short* __restrict__ Wh,   // [128][256] fp16
        const float* __restrict__ bias,          // [128]
        float* __restrict__ out) {               // [NN][128] fp32
    __shared__ __align__(16) unsigned short X[64 * XA];      // 17.4 KB
    __shared__ __align__(16) union SU {
        struct { unsigned raw[CAP]; unsigned sorted[CAP]; } s;   // 10.2 KB
        unsigned short Ws[128 * XP];                             // 18.4 KB
    } u;
    __shared__ int cnt[64], base_s[64], cur[64];
    const int t = threadIdx.x;
    const int b = blockIdx.x;
    const int n = cursor[b];

    const int lane = t & 63;
    const int w = t >> 6;
    const int quad = lane >> 4;
    const int l16 = lane & 15;

    // ---- prefetch H-half A-fragments + bias (resolve under gather) ----
    const int arow = b * 64 + w * 16 + l16;
    const bool aok = arow < NN;
    uint4 a01[2][2];
#pragma unroll
    for (int c = 0; c < 2; ++c)
#pragma unroll
        for (int kk2 = 0; kk2 < 2; ++kk2)
            a01[c][kk2] = aok
                ? *(const uint4*)(Hh + (size_t)arow * DD + c * 64 + kk2 * 32 + quad * 8)
                : make_uint4(0, 0, 0, 0);
    float bv[8];
#pragma unroll
    for (int ot = 0; ot < 8; ++ot) bv[ot] = bias[ot * 16 + l16];

    // ---- phase 1: counting sort ----
    if (t < 64) cnt[t] = 0;
    __syncthreads();
    for (int i = t; i < n; i += 256) {
        unsigned e = entries[b * CAP + i];
        u.s.raw[i] = e;
        atomicAdd(&cnt[e >> 17], 1);
    }
    __syncthreads();
    if (t < 64) {   // threads 0..63 == wave 0
        int v = cnt[t];
        int incl = v;
#pragma unroll
        for (int o = 1; o < 64; o <<= 1) {
            int y = __shfl_up(incl, o, 64);
            if (t >= o) incl += y;
        }
        base_s[t] = incl - v;
        cur[t] = incl - v;
    }
    __syncthreads();
    for (int i = t; i < n; i += 256) {
        unsigned e = u.s.raw[i];
        int pos = atomicAdd(&cur[e >> 17], 1);
        u.s.sorted[pos] = e & 0x1FFFFu;
    }
    __syncthreads();

    // ---- phase 2: gather-max -> X (aggregated half only) ----
    const int half = lane >> 5;        // 0/1: even/odd neighbor indices
    const int l32 = lane & 31;
    const _Float16* __restrict__ colbase = (const _Float16*)Hh + l32 * 4;
#pragma unroll
    for (int q = 0; q < 16; ++q) {
        int ln = w * 16 + q;
        int s0 = base_s[ln];
        int e0 = s0 + cnt[ln];
        unsigned long long mu = 0xFC00FC00FC00FC00ull;   // 4x -inf fp16
        h4_t m = *(h4_t*)&mu;
        int j = s0 + half;
        for (; j + 6 < e0; j += 8) {                     // 4 rows in flight/half
            int d0 = u.s.sorted[j], d1 = u.s.sorted[j + 2];
            int d2 = u.s.sorted[j + 4], d3 = u.s.sorted[j + 6];
            h4_t v0 = *(const h4_t*)(colbase + (size_t)d0 * DD);
            h4_t v1 = *(const h4_t*)(colbase + (size_t)d1 * DD);
            h4_t v2 = *(const h4_t*)(colbase + (size_t)d2 * DD);
            h4_t v3 = *(const h4_t*)(colbase + (size_t)d3 * DD);
            m = h4max(m, h4max(h4max(v0, v1), h4max(v2, v3)));
        }
        for (; j < e0; j += 2) {
            h4_t v0 = *(const h4_t*)(colbase + (size_t)u.s.sorted[j] * DD);
            m = h4max(m, v0);
        }
        // combine halves: each lane gets partner lane^32's partial max
        uint2 mv = *(uint2*)&m;
        uint2 ov;
        ov.x = (unsigned)__shfl_xor((int)mv.x, 32, 64);
        ov.y = (unsigned)__shfl_xor((int)mv.y, 32, 64);
        h4_t om = *(h4_t*)&ov;
        m = h4max(m, om);
        if (half == 0) {
            uint2 outv = make_uint2(0u, 0u);
            if (s0 < e0) outv = *(uint2*)&m;
            *(uint2*)&X[ln * XA + l32 * 4] = outv;
        }
    }
    __syncthreads();   // X complete; sorted dead -> Ws may overwrite

    // ---- phase 3: [Hh(prefetched) | X] @ Wh^T, wave w owns rows w*16..+15 --
    f4_t acc[8] = {};
#pragma unroll
    for (int c = 0; c < 4; ++c) {
        {
            const int seg = t & 7, o0 = t >> 3;
#pragma unroll
            for (int j = 0; j < 4; ++j) {
                int o = o0 + 32 * j;
                uint4 v = *(const uint4*)(Wh + (size_t)o * 256 + c * 64 + seg * 8);
                *(uint4*)&u.Ws[o * XP + seg * 8] = v;
            }
        }
        __syncthreads();
#pragma unroll
        for (int kk2 = 0; kk2 < 2; ++kk2) {
            h8_t a;
            if (c < 2)
                a = *(h8_t*)&a01[c][kk2];
            else
                a = *(const h8_t*)&X[(w * 16 + l16) * XA + (c - 2) * 64 + kk2 * 32 + quad * 8];
#pragma unroll
            for (int ot = 0; ot < 8; ++ot) {
                h8_t bf = *(const h8_t*)&u.Ws[(ot * 16 + l16) * XP + kk2 * 32 + quad * 8];
                acc[ot] = __builtin_amdgcn_mfma_f32_16x16x32_f16(a, bf, acc[ot], 0, 0, 0);
            }
        }
        __syncthreads();
    }

#pragma unroll
    for (int ot = 0; ot < 8; ++ot) {
#pragma unroll
        for (int reg = 0; reg < 4; ++reg) {
            int row = b * 64 + w * 16 + quad * 4 + reg;
            if (row < NN)
                out[(size_t)row * DD + ot * 16 + l16] = acc[ot][reg] + bv[ot];
        }
    }
}

extern "C" void kernel_launch(void* const* d_in, const int* in_sizes, int n_in,
                              void* d_out, int out_size, void* d_ws, size_t ws_size,
                              hipStream_t stream) {
    const float* H   = (const float*)d_in[0];
    const int*   src = (const int*)d_in[1];
    const int*   dst = (const int*)d_in[2];
    const float* W   = (const float*)d_in[3];
    const float* b   = (const float*)d_in[4];
    float* out = (float*)d_out;

    int* ws = (int*)d_ws;
    unsigned short* Hh      = (unsigned short*)(ws + WS_HH);
    int*            cursor  = ws + WS_CUR;
    unsigned*       entries = (unsigned*)(ws + WS_ENT);
    unsigned*       Wh      = (unsigned*)(ws + WS_WH);

    hipMemsetAsync(cursor, 0, NB * sizeof(int), stream);
    prep_kernel<<<PB + CB + 1, 1024, 0, stream>>>(H, src, dst, cursor, entries,
                                                  (uint4*)Hh, W, Wh);
    aggmat_kernel<<<NB, 256, 0, stream>>>(
        Hh, cursor, entries, (const unsigned short*)Wh, b, out);
}